// Round 4
// baseline (638.519 us; speedup 1.0000x reference)
//
#include <hip/hip_runtime.h>

// LSTM I=16, H=32, B=8192, T=512, fp32 — MFMA, 8-wave gate-split, K=32,
// software-pipelined ih-GEMM.
//
// Group = 16 batch rows, ONE block of 512 threads (8 waves).
// Wave wv computes ONE gate N-block: gate g = wv&3 (i,f,g,o), unit half
// uh = wv>>2. Gate pre-activations exchanged via LDS (gbuf); each lane then
// owns exactly ONE cell element (512 elems / 512 lanes).
//
// Round-4 changes vs round-3 (397 us dispatch, VALU 50% / Mfma 18% / cf 42M):
//  - ih MFMAs pipelined across the barrier: accx = bias + x[t+1]@W_ih is
//    computed in phase B of step t (MFMA pipe overlaps the cell-update VALU
//    chain); phase A's dependent MFMA chain is 3 deep instead of 5.
//    Accumulation ORDER is unchanged -> bit-identical gates.
//  - gbuf row stride 33 -> 34 f32 words: publish bank = (8q+2r+m)%32, each
//    bank hit exactly 2x (free per m136); stride 33 was a 4-way conflict
//    (bank = (4q+r+m)%32). Gather stays 2-way free: (2*eR+eu)%32.
//
// Precision: split-bf16. gates = (x1+x2)@W1 + (x1+x2)@W2 (ih)
//          + h1@W1 + h2@W1 + h1@W2 (hh; h2@W2 dropped, < 1e-4).
// MFMA 16x16x32 bf16 fragment mapping (m89/m92-verified family):
//   A: lane(m=L&15, q=L>>4) holds A[m][k=8q+j], j=0..7 (contiguous k)
//   B: lane(n=L&15, q)      holds B[k=8q+j][n]
//   C/D: lane holds D[row=4q+reg][col=n]

typedef float f4 __attribute__((ext_vector_type(4)));
typedef __bf16 bf8v __attribute__((ext_vector_type(8)));

constexpr int ISZ = 16, HSZ = 32, TT = 512, BB = 8192;
constexpr int HSTR = 72;  // bf16/row: [h1(32)|h2(32)] + 8 pad -> 144B
constexpr int XSTR = 40;  // bf16/row: [x1(16)|x2(16)] + 8 pad -> 80B
constexpr int GSTR = 34;  // f32/row: publish/gather both 2-way (conflict-free)

#define MFMA32(a, b, c) __builtin_amdgcn_mfma_f32_16x16x32_bf16((a), (b), (c), 0, 0, 0)

__device__ __forceinline__ float fsig(float x) {
  return __builtin_amdgcn_rcpf(1.0f + __builtin_amdgcn_exp2f(-1.44269504f * x));
}

// split 8 fp32 -> hi/lo bf16 fragments (RNE split: v = hi + lo + O(2^-16 v))
__device__ __forceinline__ void split8(const float* v, bf8v& hi, bf8v& lo) {
#pragma unroll
  for (int i = 0; i < 8; ++i) {
    const __bf16 h = (__bf16)v[i];
    hi[i] = h;
    lo[i] = (__bf16)(v[i] - (float)h);
  }
}

__global__ __launch_bounds__(512, 4) void lstm_mfma(
    const float* __restrict__ x, const float* __restrict__ W_ih,
    const float* __restrict__ W_hh, const float* __restrict__ b_ih,
    const float* __restrict__ b_hh, const float* __restrict__ W_fc,
    const float* __restrict__ b_fc, float* __restrict__ out) {
  // h planes: [buf][row 16][72 bf16] = 4608 B (packed h1|h2, double-buffered)
  __shared__ __align__(16) __bf16 hl[2][16][HSTR];
  // x planes: [buf][row 16][40 bf16] = 2560 B (packed x1|x2, double-buffered)
  __shared__ __align__(16) __bf16 xs[2][16][XSTR];
  // gate exchange: [gate][batch row][34 f32] = 8704 B
  __shared__ __align__(16) float gbuf[4][16][GSTR];

  const int tid = threadIdx.x;
  const int wv = tid >> 6;       // wave 0..7
  const int g = wv & 3;          // gate (i,f,g,o) of this wave's N-block
  const int uh = wv >> 2;        // unit half
  const int L = tid & 63;
  const int m = L & 15;          // M (batch row) for A/C; N (unit) for B
  const int q = L >> 4;          // quad
  const int row0 = blockIdx.x * 16;
  const int uw = uh * 16 + m;    // unit column of this wave's acc
  const int j = g * 32 + uw;     // gate row in the 4H dim

  // owned cell element
  const int eR = wv * 2 + (L >> 5);  // batch row 0..15
  const int eu = L & 31;             // unit 0..31

  // ---- load + split weights for this wave's gate row (once) ----
  bf8v bih1, bih2, bhh1, bhh2;
  f4 biasv;
  {
    float wh[8];
    *(f4*)&wh[0] = *(const f4*)(W_hh + j * HSZ + 8 * q);
    *(f4*)&wh[4] = *(const f4*)(W_hh + j * HSZ + 8 * q + 4);
    split8(wh, bhh1, bhh2);
    float wi[8];
    const int k8 = (q & 1) * 8;  // B rows k>=16 wrap to W_ih k-16
    *(f4*)&wi[0] = *(const f4*)(W_ih + j * ISZ + k8);
    *(f4*)&wi[4] = *(const f4*)(W_ih + j * ISZ + k8 + 4);
    split8(wi, bih1, bih2);
    const float bb = b_ih[j] + b_hh[j];
    biasv = (f4){bb, bb, bb, bb};
  }

  // ---- zero h buffers; stage split-x for t=0 ----
  for (int i = tid; i < 2 * 16 * HSTR; i += 512) ((__bf16*)hl)[i] = (__bf16)0.0f;
  const int xr = tid >> 4, xi = tid & 15;  // x staging duty (lanes 0..255)
  const float* xbase = x + (size_t)(row0 + xr) * TT * ISZ + xi;
  if (tid < 256) {
    const float v = xbase[0];
    const __bf16 h = (__bf16)v;
    xs[0][xr][xi] = h;
    xs[0][xr][16 + xi] = (__bf16)(v - (float)h);
  }
  __syncthreads();

  // ---- prologue: accx(t=0) = bias + x[0]@W_ih; preload x[1] ----
  bf8v axn = *(const bf8v*)&xs[0][m][8 * q];
  f4 accx = MFMA32(axn, bih1, biasv);
  accx = MFMA32(axn, bih2, accx);
  float xnext = 0.0f;
  if (tid < 256) xnext = xbase[ISZ];  // x[1]

  float cst = 0.0f;  // cell state of the ONE owned element

  for (int t = 0; t < TT; ++t) {
    const int p = t & 1;
    // ---- phase A: hh chain (3 deep) on top of pipelined accx ----
    const bf8v ah1 = *(const bf8v*)&hl[p][m][8 * q];
    const bf8v ah2 = *(const bf8v*)&hl[p][m][32 + 8 * q];

    // stage split-x[t+1] into xs[p^1] (read by phase B after b1)
    if (tid < 256) {
      const __bf16 xh = (__bf16)xnext;
      xs[p ^ 1][xr][xi] = xh;
      xs[p ^ 1][xr][16 + xi] = (__bf16)(xnext - (float)xh);
    }

    f4 a = MFMA32(ah1, bhh1, accx);  // h1@W1
    a = MFMA32(ah2, bhh1, a);        // h2@W1
    a = MFMA32(ah1, bhh2, a);        // h1@W2

    // publish this wave's gate block: rows 4q+r, column uw (2-way, free)
#pragma unroll
    for (int r = 0; r < 4; ++r) gbuf[g][q * 4 + r][uw] = a[r];
    __syncthreads();  // b1: gbuf + xs[p^1] ready

    // ---- phase B ----
    // issue next global x load early (consumed next iteration)
    const int tl = (t + 2 < TT) ? t + 2 : TT - 1;
    if (tid < 256) xnext = xbase[(size_t)tl * ISZ];

    // pipelined ih MFMAs for t+1 (MFMA pipe, overlaps cell-update VALU)
    axn = *(const bf8v*)&xs[p ^ 1][m][8 * q];
    accx = MFMA32(axn, bih1, biasv);
    accx = MFMA32(axn, bih2, accx);

    // gather all 4 gates of the owned element
    const float vi = gbuf[0][eR][eu];
    const float vf = gbuf[1][eR][eu];
    const float vg = gbuf[2][eR][eu];
    const float vo = gbuf[3][eR][eu];

    const float ig = fsig(vi);
    const float fg = fsig(vf);
    const float gv = 2.0f * fsig(2.0f * vg) - 1.0f;  // tanh(g)
    const float og = fsig(vo);
    const float cc = fg * cst + ig * gv;
    cst = cc;
    const float th = 2.0f * fsig(2.0f * cc) - 1.0f;  // tanh(c)
    const float h = og * th;
    const __bf16 h1 = (__bf16)h;
    hl[p ^ 1][eR][eu] = h1;
    hl[p ^ 1][eR][32 + eu] = (__bf16)(h - (float)h1);
    __syncthreads();  // b2: h[t+1] ready; gbuf reads drained
  }

  // ---- epilogue: out[row] = sum_u h[row][u]*W_fc[u] + b_fc ----
  // final h (t=TT) is in buf[0] (TT even)
  if (tid < 16) {
    float s = b_fc[0];
#pragma unroll 8
    for (int uu = 0; uu < HSZ; ++uu) {
      const float h = (float)hl[0][tid][uu] + (float)hl[0][tid][32 + uu];
      s += h * W_fc[uu];
    }
    out[row0 + tid] = s;
  }
}

extern "C" void kernel_launch(void* const* d_in, const int* in_sizes, int n_in,
                              void* d_out, int out_size, void* d_ws, size_t ws_size,
                              hipStream_t stream) {
  const float* x    = (const float*)d_in[0];
  const float* W_ih = (const float*)d_in[1];
  const float* W_hh = (const float*)d_in[2];
  const float* b_ih = (const float*)d_in[3];
  const float* b_hh = (const float*)d_in[4];
  const float* W_fc = (const float*)d_in[5];
  const float* b_fc = (const float*)d_in[6];
  float* out = (float*)d_out;

  dim3 grid(BB / 16);   // 512 blocks = 512 row-groups
  dim3 block(512);      // 8 waves per group (gate x unit-half split)
  lstm_mfma<<<grid, block, 0, stream>>>(x, W_ih, W_hh, b_ih, b_hh, W_fc, b_fc, out);
}